// Round 1
// 819.447 us; speedup vs baseline: 1.0220x; 1.0220x over previous
//
#include <hip/hip_runtime.h>
#include <math.h>

#define R 1024
#define CIN 256
#define NH 8
#define CZ 128
#define EPS 1e-5f
#define SROW 1028  // padded score row stride (floats): rows 16B-aligned, banks offset by 4/row

// ---- DPP row reductions: cross-lane adds on the VALU pipe (no DS traffic) ----
// 0xB1 = quad_perm(1,0,3,2)  -> xor1
// 0x4E = quad_perm(2,3,0,1)  -> xor2
// 0x141 = row_half_mirror    -> combines 4-groups within 8
// 0x140 = row_mirror         -> combines 8-groups within 16
#define DPPADD(v, ctrl) \
    v += __int_as_float(__builtin_amdgcn_update_dpp(0, __float_as_int(v), ctrl, 0xf, 0xf, true))
#define RED16(v) { DPPADD(v, 0xB1); DPPADD(v, 0x4E); DPPADD(v, 0x141); DPPADD(v, 0x140); }
#define RED8(v)  { DPPADD(v, 0xB1); DPPADD(v, 0x4E); DPPADD(v, 0x141); }

// ---------------- K1: fused LayerNorm(m) + QS/KS/VS/GS = mn @ {Wq,Wk,Wv,Wg} ----------------
__global__ __launch_bounds__(256) void k_qkvg(const float* __restrict__ m,
        const float* __restrict__ lmw, const float* __restrict__ lmb,
        const float* __restrict__ Wq, const float* __restrict__ Wk,
        const float* __restrict__ Wv, const float* __restrict__ Wg,
        float* __restrict__ QS, float* __restrict__ KS,
        float* __restrict__ VS, float* __restrict__ GS) {
    __shared__ __align__(16) float mnt[CIN * 4];   // mnt[c][r]
    __shared__ float red[32];                      // [wave][{s1[4],s2[4]}]
    int tid = threadIdx.x;
    int mat = blockIdx.x >> 8;
    int qb = (blockIdx.x & 255) * 4;

    // ---- fused LN over the 4 rows this block needs (redundant across 4 mats, trivial) ----
    float w_ln = lmw[tid], b_ln = lmb[tid];
    float x[4];
    #pragma unroll
    for (int r = 0; r < 4; ++r) x[r] = m[(size_t)(qb + r) * CIN + tid];
    #pragma unroll
    for (int r = 0; r < 4; ++r) {
        float a = x[r], bq = x[r] * x[r];
        RED16(a); RED16(bq);
        a += __shfl_xor(a, 16); bq += __shfl_xor(bq, 16);
        a += __shfl_xor(a, 32); bq += __shfl_xor(bq, 32);
        if ((tid & 63) == 0) { red[(tid >> 6) * 8 + r] = a; red[(tid >> 6) * 8 + 4 + r] = bq; }
    }
    __syncthreads();
    #pragma unroll
    for (int r = 0; r < 4; ++r) {
        float t1 = red[r] + red[8 + r] + red[16 + r] + red[24 + r];
        float t2 = red[4 + r] + red[12 + r] + red[20 + r] + red[28 + r];
        float mu = t1 * (1.0f / CIN);
        float var = t2 * (1.0f / CIN) - mu * mu;
        float rstd = rsqrtf(var + EPS);
        mnt[tid * 4 + r] = (x[r] - mu) * rstd * w_ln + b_ln;
    }
    __syncthreads();

    const float* W = (mat == 0) ? Wq : (mat == 1) ? Wk : (mat == 2) ? Wv : Wg;
    const float4* mt4 = (const float4*)mnt;
    float acc[4] = {0.f, 0.f, 0.f, 0.f};
    #pragma unroll 4
    for (int g = 0; g < 32; ++g) {
        float w0 = W[(g * 8 + 0) * 256 + tid];
        float w1 = W[(g * 8 + 1) * 256 + tid];
        float w2 = W[(g * 8 + 2) * 256 + tid];
        float w3 = W[(g * 8 + 3) * 256 + tid];
        float w4 = W[(g * 8 + 4) * 256 + tid];
        float w5 = W[(g * 8 + 5) * 256 + tid];
        float w6 = W[(g * 8 + 6) * 256 + tid];
        float w7 = W[(g * 8 + 7) * 256 + tid];
        #pragma unroll
        for (int u = 0; u < 8; ++u) {
            float wv = (u == 0) ? w0 : (u == 1) ? w1 : (u == 2) ? w2 : (u == 3) ? w3
                     : (u == 4) ? w4 : (u == 5) ? w5 : (u == 6) ? w6 : w7;
            float4 mv = mt4[g * 8 + u];
            acc[0] += mv.x * wv; acc[1] += mv.y * wv;
            acc[2] += mv.z * wv; acc[3] += mv.w * wv;
        }
    }
    float* OUT = (mat == 0) ? QS : (mat == 1) ? KS : (mat == 2) ? VS : GS;
    #pragma unroll
    for (int r = 0; r < 4; ++r) {
        float v = acc[r];
        if (mat == 0) v *= 0.17677669529663687f;      // 1/sqrt(32)
        if (mat == 3) v = 1.f / (1.f + __expf(-v));   // sigmoid
        OUT[(qb + r) * 256 + tid] = v;
    }
}

#define FMA4(acc, s, c) { acc.x += (s)*(c).x; acc.y += (s)*(c).y; \
                          acc.z += (s)*(c).z; acc.w += (s)*(c).w; }

// ---------------- K2: fused pair-bias(z) + attention + gate ----------------
// All cross-lane reductions via DPP (VALU pipe); DS pipe reserved for score staging.
__global__ __launch_bounds__(256, 4) void k_attn(
        const float* __restrict__ z, const float* __restrict__ lzw,
        const float* __restrict__ lzb, const float* __restrict__ Wz,
        const float* __restrict__ QS, const float* __restrict__ KS,
        const float* __restrict__ VS, const float* __restrict__ GS,
        float* __restrict__ OB) {
    __shared__ __align__(16) float s_lds[NH * SROW];   // ~32.9 KB scores [h][k]
    __shared__ __align__(16) float aux[CZ * NH];       // A (prep), then PV partials (4KB)
    __shared__ float sumA[NH], constB[NH], inv_lds[NH];
    const int tid = threadIdx.x;
    const int q = blockIdx.x;
    const int w = tid >> 6;     // wave 0..3, owns k in [w*256, w*256+256)
    const int l = tid & 63;
    const int j0 = l & 15;      // column sub-index within a z row
    const int row = l >> 4;     // row 0..3 within a 4-row group

    // ---- prep: A[c][h] = lzw[c] * Wz[c][h] into aux ----
    if (tid < CZ) {
        float lw = lzw[tid];
        #pragma unroll
        for (int h = 0; h < NH; ++h) aux[tid * NH + h] = lw * Wz[tid * NH + h];
    }
    __syncthreads();
    if (tid < NH) {
        float sa = 0.f, cb = 0.f;
        for (int c = 0; c < CZ; ++c) {
            sa += aux[c * NH + tid];
            cb += lzb[c] * Wz[c * NH + tid];
        }
        sumA[tid] = sa; constB[tid] = cb;
    }
    // lane-private A columns: c = j0*4 + u*64 + e  (fixed for the whole k-loop)
    float4 al[2][4][2];
    #pragma unroll
    for (int u = 0; u < 2; ++u)
        #pragma unroll
        for (int e = 0; e < 4; ++e) {
            int c = j0 * 4 + u * 64 + e;
            al[u][e][0] = *(const float4*)(aux + c * NH);
            al[u][e][1] = *(const float4*)(aux + c * NH + 4);
        }

    // ---- phase A: s[h][k] = q . k  (coalesced K rows, DPP reduce over 8 lanes) ----
    {
        const float4 q4 = ((const float4*)(QS + (size_t)q * CIN))[l];
        const float4* K4 = (const float4*)KS;
        const int h = l >> 3;                  // head for cols 4l..4l+3
        float* sdst = s_lds + h * SROW;
        for (int i = 0; i < 256; i += 4) {
            int k0 = (w << 8) + i;
            float4 kv0 = K4[(size_t)(k0 + 0) * 64 + l];
            float4 kv1 = K4[(size_t)(k0 + 1) * 64 + l];
            float4 kv2 = K4[(size_t)(k0 + 2) * 64 + l];
            float4 kv3 = K4[(size_t)(k0 + 3) * 64 + l];
            float d0 = kv0.x*q4.x + kv0.y*q4.y + kv0.z*q4.z + kv0.w*q4.w;
            float d1 = kv1.x*q4.x + kv1.y*q4.y + kv1.z*q4.z + kv1.w*q4.w;
            float d2 = kv2.x*q4.x + kv2.y*q4.y + kv2.z*q4.z + kv2.w*q4.w;
            float d3 = kv3.x*q4.x + kv3.y*q4.y + kv3.z*q4.z + kv3.w*q4.w;
            RED8(d0); RED8(d1); RED8(d2); RED8(d3);
            if ((l & 7) == 0)
                *(float4*)(sdst + k0) = make_float4(d0, d1, d2, d3);
        }
    }
    __syncthreads();

    // ---- phase B: += pair bias from z (coalesced; DPP reduce over 16 lanes) ----
    {
        const float4* zb4 = (const float4*)(z + ((size_t)q * R + (size_t)(w << 8)) * CZ);
        const int rb = row * 32 + j0;
        auto process = [&](int g, const float4 v0, const float4 v1) {
            int k = (w << 8) + (g << 2) + row;
            float s1 = v0.x + v0.y + v0.z + v0.w + v1.x + v1.y + v1.z + v1.w;
            float s2 = v0.x*v0.x + v0.y*v0.y + v0.z*v0.z + v0.w*v0.w
                     + v1.x*v1.x + v1.y*v1.y + v1.z*v1.z + v1.w*v1.w;
            float4 da = make_float4(0.f, 0.f, 0.f, 0.f);
            float4 db = make_float4(0.f, 0.f, 0.f, 0.f);
            FMA4(da, v0.x, al[0][0][0]); FMA4(db, v0.x, al[0][0][1]);
            FMA4(da, v0.y, al[0][1][0]); FMA4(db, v0.y, al[0][1][1]);
            FMA4(da, v0.z, al[0][2][0]); FMA4(db, v0.z, al[0][2][1]);
            FMA4(da, v0.w, al[0][3][0]); FMA4(db, v0.w, al[0][3][1]);
            FMA4(da, v1.x, al[1][0][0]); FMA4(db, v1.x, al[1][0][1]);
            FMA4(da, v1.y, al[1][1][0]); FMA4(db, v1.y, al[1][1][1]);
            FMA4(da, v1.z, al[1][2][0]); FMA4(db, v1.z, al[1][2][1]);
            FMA4(da, v1.w, al[1][3][0]); FMA4(db, v1.w, al[1][3][1]);
            RED16(s1);   RED16(s2);
            RED16(da.x); RED16(da.y); RED16(da.z); RED16(da.w);
            RED16(db.x); RED16(db.y); RED16(db.z); RED16(db.w);
            float mu = s1 * (1.0f / CZ);
            float var = s2 * (1.0f / CZ) - mu * mu;
            float rstd = rsqrtf(var + EPS);
            if (j0 < 8) {
                float dh = (j0 & 4) ? ((j0 & 2) ? ((j0 & 1) ? db.w : db.z)
                                                : ((j0 & 1) ? db.y : db.x))
                                    : ((j0 & 2) ? ((j0 & 1) ? da.w : da.z)
                                                : ((j0 & 1) ? da.y : da.x));
                float bias = rstd * (dh - mu * sumA[j0]) + constB[j0];
                s_lds[j0 * SROW + k] += bias;
            }
        };
        float4 A0 = zb4[rb], A1 = zb4[rb + 16];
        for (int g = 0; g < 64; ++g) {
            int gn = (g + 1) & 63;
            float4 N0 = zb4[rb + gn * 128];
            float4 N1 = zb4[rb + gn * 128 + 16];
            process(g, A0, A1);
            A0 = N0; A1 = N1;
        }
    }
    __syncthreads();

    // ---- phase C: softmax per head (32 lanes per head) ----
    {
        int r = tid >> 5, j = tid & 31;
        float* srow = s_lds + r * SROW;
        float mx = -1e30f;
        #pragma unroll 4
        for (int i = 0; i < 32; ++i) mx = fmaxf(mx, srow[j + i * 32]);
        #pragma unroll
        for (int mm = 1; mm < 32; mm <<= 1) mx = fmaxf(mx, __shfl_xor(mx, mm));
        float sum = 0.f;
        #pragma unroll 4
        for (int i = 0; i < 32; ++i) {
            float e = __expf(srow[j + i * 32] - mx);
            srow[j + i * 32] = e;
            sum += e;
        }
        #pragma unroll
        for (int mm = 1; mm < 32; mm <<= 1) sum += __shfl_xor(sum, mm);
        if (j == 0) inv_lds[r] = 1.f / sum;
    }
    __syncthreads();

    // ---- phase D: o = P.V (coalesced V rows, P via float4 LDS broadcast) ----
    {
        const float4* V4 = (const float4*)VS;
        const int h = l >> 3;
        const float* prow = s_lds + h * SROW;
        float4 o = make_float4(0.f, 0.f, 0.f, 0.f);
        for (int i = 0; i < 256; i += 4) {
            int k0 = (w << 8) + i;
            float4 v0 = V4[(size_t)(k0 + 0) * 64 + l];
            float4 v1 = V4[(size_t)(k0 + 1) * 64 + l];
            float4 v2 = V4[(size_t)(k0 + 2) * 64 + l];
            float4 v3 = V4[(size_t)(k0 + 3) * 64 + l];
            float4 p4 = *(const float4*)(prow + k0);
            FMA4(o, p4.x, v0); FMA4(o, p4.y, v1); FMA4(o, p4.z, v2); FMA4(o, p4.w, v3);
        }
        ((float4*)aux)[w * 64 + l] = o;   // aux[w*256 + 4l..4l+3]
    }
    __syncthreads();
    {
        float s = aux[tid] + aux[256 + tid] + aux[512 + tid] + aux[768 + tid];
        float o = s * inv_lds[tid >> 5] * GS[(size_t)q * CIN + tid];
        OB[(size_t)q * CIN + tid] = o;
    }
}

// ---------------- K3: out = OB @ Wo + bo ----------------
__global__ __launch_bounds__(256) void k_out(const float* __restrict__ OB,
        const float* __restrict__ Wo, const float* __restrict__ bo,
        float* __restrict__ out) {
    __shared__ __align__(16) float mnt[CIN * 4];
    int tid = threadIdx.x;
    int qb = blockIdx.x * 4;
    #pragma unroll
    for (int r = 0; r < 4; ++r)
        mnt[tid * 4 + r] = OB[(qb + r) * CIN + tid];
    __syncthreads();
    const float4* mt4 = (const float4*)mnt;
    float acc[4] = {0.f, 0.f, 0.f, 0.f};
    #pragma unroll 4
    for (int g = 0; g < 32; ++g) {
        #pragma unroll
        for (int u = 0; u < 8; ++u) {
            float wv = Wo[(g * 8 + u) * 256 + tid];
            float4 mv = mt4[g * 8 + u];
            acc[0] += mv.x * wv; acc[1] += mv.y * wv;
            acc[2] += mv.z * wv; acc[3] += mv.w * wv;
        }
    }
    float bv = bo[tid];
    #pragma unroll
    for (int r = 0; r < 4; ++r)
        out[(qb + r) * 256 + tid] = acc[r] + bv;
}

extern "C" void kernel_launch(void* const* d_in, const int* in_sizes, int n_in,
                              void* d_out, int out_size, void* d_ws, size_t ws_size,
                              hipStream_t stream) {
    (void)in_sizes; (void)n_in; (void)out_size; (void)ws_size;
    const float* m   = (const float*)d_in[0];
    const float* z   = (const float*)d_in[1];
    const float* lmw = (const float*)d_in[2];
    const float* lmb = (const float*)d_in[3];
    const float* lzw = (const float*)d_in[4];
    const float* lzb = (const float*)d_in[5];
    const float* Wz  = (const float*)d_in[6];
    const float* Wq  = (const float*)d_in[7];
    const float* Wk  = (const float*)d_in[8];
    const float* Wv  = (const float*)d_in[9];
    const float* Wg  = (const float*)d_in[10];
    const float* Wo  = (const float*)d_in[12];
    const float* bo  = (const float*)d_in[13];
    float* ws = (float*)d_ws;
    float* QS = ws + 262144;
    float* KS = ws + 524288;
    float* VS = ws + 786432;
    float* GS = ws + 1048576;
    float* OB = ws + 1310720;
    float* out = (float*)d_out;

    hipLaunchKernelGGL(k_qkvg, dim3(1024), dim3(256), 0, stream,
                       m, lmw, lmb, Wq, Wk, Wv, Wg, QS, KS, VS, GS);
    hipLaunchKernelGGL(k_attn, dim3(R), dim3(256), 0, stream,
                       z, lzw, lzb, Wz, QS, KS, VS, GS, OB);
    hipLaunchKernelGGL(k_out, dim3(256), dim3(256), 0, stream, OB, Wo, bo, out);
}

// Round 2
// 800.514 us; speedup vs baseline: 1.0462x; 1.0237x over previous
//
#include <hip/hip_runtime.h>
#include <math.h>

#define R 1024
#define CIN 256
#define NH 8
#define CZ 128
#define EPS 1e-5f
#define SROW 1028  // score row stride: 16B-aligned, per-row bank offset 4

// ---- DPP cross-lane reductions (VALU pipe, no DS traffic) ----
#define DPPADD(v, ctrl) \
    v += __int_as_float(__builtin_amdgcn_update_dpp(0, __float_as_int(v), ctrl, 0xf, 0xf, true))
#define DPPMAX(v, ctrl) \
    v = fmaxf(v, __int_as_float(__builtin_amdgcn_update_dpp(0, __float_as_int(v), ctrl, 0xf, 0xf, true)))
#define RED16(v)    { DPPADD(v, 0xB1); DPPADD(v, 0x4E); DPPADD(v, 0x141); DPPADD(v, 0x140); }
#define RED8(v)     { DPPADD(v, 0xB1); DPPADD(v, 0x4E); DPPADD(v, 0x141); }
#define RED16MAX(v) { DPPMAX(v, 0xB1); DPPMAX(v, 0x4E); DPPMAX(v, 0x141); DPPMAX(v, 0x140); }

// ---------------- K1: fused LN(m) + 2 of {Q,K,V,G} projections per block ----------------
// 512 blocks: mp=0 -> {Wq,Wk}, mp=1 -> {Wv,Wg}. One LDS b128 read feeds 2 matrices.
__global__ __launch_bounds__(256) void k_qkvg(const float* __restrict__ m,
        const float* __restrict__ lmw, const float* __restrict__ lmb,
        const float* __restrict__ Wq, const float* __restrict__ Wk,
        const float* __restrict__ Wv, const float* __restrict__ Wg,
        float* __restrict__ QS, float* __restrict__ KS,
        float* __restrict__ VS, float* __restrict__ GS) {
    __shared__ __align__(16) float mnt[CIN * 4];   // mnt[c][r]
    __shared__ float red[32];
    int tid = threadIdx.x;
    int mp = blockIdx.x >> 8;
    int qb = (blockIdx.x & 255) * 4;

    float w_ln = lmw[tid], b_ln = lmb[tid];
    float x[4];
    #pragma unroll
    for (int r = 0; r < 4; ++r) x[r] = m[(size_t)(qb + r) * CIN + tid];
    #pragma unroll
    for (int r = 0; r < 4; ++r) {
        float a = x[r], bq = x[r] * x[r];
        RED16(a); RED16(bq);
        a += __shfl_xor(a, 16); bq += __shfl_xor(bq, 16);
        a += __shfl_xor(a, 32); bq += __shfl_xor(bq, 32);
        if ((tid & 63) == 0) { red[(tid >> 6) * 8 + r] = a; red[(tid >> 6) * 8 + 4 + r] = bq; }
    }
    __syncthreads();
    #pragma unroll
    for (int r = 0; r < 4; ++r) {
        float t1 = red[r] + red[8 + r] + red[16 + r] + red[24 + r];
        float t2 = red[4 + r] + red[12 + r] + red[20 + r] + red[28 + r];
        float mu = t1 * (1.0f / CIN);
        float var = t2 * (1.0f / CIN) - mu * mu;
        float rstd = rsqrtf(var + EPS);
        mnt[tid * 4 + r] = (x[r] - mu) * rstd * w_ln + b_ln;
    }
    __syncthreads();

    const float* Wa = mp ? Wv : Wq;
    const float* Wb = mp ? Wg : Wk;
    const float4* mt4 = (const float4*)mnt;
    float acca[4] = {0.f, 0.f, 0.f, 0.f};
    float accb[4] = {0.f, 0.f, 0.f, 0.f};
    #pragma unroll 2
    for (int g = 0; g < 32; ++g) {
        float wa[8], wb[8];
        #pragma unroll
        for (int u = 0; u < 8; ++u) {
            wa[u] = Wa[(g * 8 + u) * 256 + tid];
            wb[u] = Wb[(g * 8 + u) * 256 + tid];
        }
        #pragma unroll
        for (int u = 0; u < 8; ++u) {
            float4 mv = mt4[g * 8 + u];
            acca[0] += mv.x * wa[u]; acca[1] += mv.y * wa[u];
            acca[2] += mv.z * wa[u]; acca[3] += mv.w * wa[u];
            accb[0] += mv.x * wb[u]; accb[1] += mv.y * wb[u];
            accb[2] += mv.z * wb[u]; accb[3] += mv.w * wb[u];
        }
    }
    float* Oa = mp ? VS : QS;
    float* Ob = mp ? GS : KS;
    #pragma unroll
    for (int r = 0; r < 4; ++r) {
        float va = acca[r];
        float vb = accb[r];
        if (mp == 0) va *= 0.17677669529663687f;           // q scale 1/sqrt(32)
        if (mp == 1) vb = 1.f / (1.f + __expf(-vb));       // sigmoid gate
        Oa[(qb + r) * 256 + tid] = va;
        Ob[(qb + r) * 256 + tid] = vb;
    }
}

#define FMA4(acc, s, c) { acc.x += (s)*(c).x; acc.y += (s)*(c).y; \
                          acc.z += (s)*(c).z; acc.w += (s)*(c).w; }

// ---------------- K2: fused pair-bias(z) + attention + gate + out-proj ----------------
// 2 q-rows per block (512 blocks): halves KS/VS L2 traffic. Dynamic LDS for scores.
__global__ __launch_bounds__(256, 2) void k_attn(
        const float* __restrict__ z, const float* __restrict__ lzw,
        const float* __restrict__ lzb, const float* __restrict__ Wz,
        const float* __restrict__ QS, const float* __restrict__ KS,
        const float* __restrict__ VS, const float* __restrict__ GS,
        const float* __restrict__ Wo, const float* __restrict__ bo,
        float* __restrict__ out) {
    extern __shared__ __align__(16) float sc[];        // [2*NH][SROW] scores (65792 B)
    __shared__ __align__(16) float aux[2048];          // prep A (1024), then PV partials (2048)
    __shared__ __align__(16) float obr[2][CIN];        // gated attention output rows
    __shared__ float sumA[NH], constB[NH], inv_lds[16];
    const int tid = threadIdx.x;
    const int q0 = blockIdx.x * 2;
    const int w = tid >> 6;     // wave 0..3, owns k in [w*256, w*256+256)
    const int l = tid & 63;
    const int j0 = l & 15;
    const int row = l >> 4;

    // ---- prep: A[c][h] = lzw[c] * Wz[c][h] ----
    if (tid < CZ) {
        float lw = lzw[tid];
        #pragma unroll
        for (int h = 0; h < NH; ++h) aux[tid * NH + h] = lw * Wz[tid * NH + h];
    }
    __syncthreads();
    if (tid < NH) {
        float sa = 0.f, cb = 0.f;
        for (int c = 0; c < CZ; ++c) {
            sa += aux[c * NH + tid];
            cb += lzb[c] * Wz[c * NH + tid];
        }
        sumA[tid] = sa; constB[tid] = cb;
    }
    float4 al[2][4][2];
    #pragma unroll
    for (int u = 0; u < 2; ++u)
        #pragma unroll
        for (int e = 0; e < 4; ++e) {
            int c = j0 * 4 + u * 64 + e;
            al[u][e][0] = *(const float4*)(aux + c * NH);
            al[u][e][1] = *(const float4*)(aux + c * NH + 4);
        }

    // ---- phase A: scores = q.k for both q rows (K tile read once) ----
    {
        const float4 qa = ((const float4*)(QS + (size_t)q0 * CIN))[l];
        const float4 qb = ((const float4*)(QS + (size_t)(q0 + 1) * CIN))[l];
        const float4* K4 = (const float4*)KS;
        const int h = l >> 3;
        float* sd0 = sc + h * SROW;
        float* sd1 = sc + (NH + h) * SROW;
        for (int i = 0; i < 256; i += 4) {
            int k0 = (w << 8) + i;
            float4 kv0 = K4[(size_t)(k0 + 0) * 64 + l];
            float4 kv1 = K4[(size_t)(k0 + 1) * 64 + l];
            float4 kv2 = K4[(size_t)(k0 + 2) * 64 + l];
            float4 kv3 = K4[(size_t)(k0 + 3) * 64 + l];
            float d0a = kv0.x*qa.x + kv0.y*qa.y + kv0.z*qa.z + kv0.w*qa.w;
            float d1a = kv1.x*qa.x + kv1.y*qa.y + kv1.z*qa.z + kv1.w*qa.w;
            float d2a = kv2.x*qa.x + kv2.y*qa.y + kv2.z*qa.z + kv2.w*qa.w;
            float d3a = kv3.x*qa.x + kv3.y*qa.y + kv3.z*qa.z + kv3.w*qa.w;
            float d0b = kv0.x*qb.x + kv0.y*qb.y + kv0.z*qb.z + kv0.w*qb.w;
            float d1b = kv1.x*qb.x + kv1.y*qb.y + kv1.z*qb.z + kv1.w*qb.w;
            float d2b = kv2.x*qb.x + kv2.y*qb.y + kv2.z*qb.z + kv2.w*qb.w;
            float d3b = kv3.x*qb.x + kv3.y*qb.y + kv3.z*qb.z + kv3.w*qb.w;
            RED8(d0a); RED8(d1a); RED8(d2a); RED8(d3a);
            RED8(d0b); RED8(d1b); RED8(d2b); RED8(d3b);
            if ((l & 7) == 0) {
                *(float4*)(sd0 + k0) = make_float4(d0a, d1a, d2a, d3a);
                *(float4*)(sd1 + k0) = make_float4(d0b, d1b, d2b, d3b);
            }
        }
    }
    __syncthreads();

    // ---- phase B: += pair bias from z, both q rows, 1-iter-deep prefetch ----
    {
        const float4* zb0 = (const float4*)(z + ((size_t)q0 * R + (size_t)(w << 8)) * CZ);
        const float4* zb1 = zb0 + (size_t)R * CZ / 4;
        const int rb = row * 32 + j0;
        auto process = [&](int qq, int g, const float4 v0, const float4 v1) {
            int k = (w << 8) + (g << 2) + row;
            float s1 = v0.x + v0.y + v0.z + v0.w + v1.x + v1.y + v1.z + v1.w;
            float s2 = v0.x*v0.x + v0.y*v0.y + v0.z*v0.z + v0.w*v0.w
                     + v1.x*v1.x + v1.y*v1.y + v1.z*v1.z + v1.w*v1.w;
            float4 da = make_float4(0.f, 0.f, 0.f, 0.f);
            float4 db = make_float4(0.f, 0.f, 0.f, 0.f);
            FMA4(da, v0.x, al[0][0][0]); FMA4(db, v0.x, al[0][0][1]);
            FMA4(da, v0.y, al[0][1][0]); FMA4(db, v0.y, al[0][1][1]);
            FMA4(da, v0.z, al[0][2][0]); FMA4(db, v0.z, al[0][2][1]);
            FMA4(da, v0.w, al[0][3][0]); FMA4(db, v0.w, al[0][3][1]);
            FMA4(da, v1.x, al[1][0][0]); FMA4(db, v1.x, al[1][0][1]);
            FMA4(da, v1.y, al[1][1][0]); FMA4(db, v1.y, al[1][1][1]);
            FMA4(da, v1.z, al[1][2][0]); FMA4(db, v1.z, al[1][2][1]);
            FMA4(da, v1.w, al[1][3][0]); FMA4(db, v1.w, al[1][3][1]);
            RED16(s1);   RED16(s2);
            RED16(da.x); RED16(da.y); RED16(da.z); RED16(da.w);
            RED16(db.x); RED16(db.y); RED16(db.z); RED16(db.w);
            float mu = s1 * (1.0f / CZ);
            float var = s2 * (1.0f / CZ) - mu * mu;
            float rstd = rsqrtf(var + EPS);
            if (j0 < 8) {
                float dh = (j0 & 4) ? ((j0 & 2) ? ((j0 & 1) ? db.w : db.z)
                                                : ((j0 & 1) ? db.y : db.x))
                                    : ((j0 & 2) ? ((j0 & 1) ? da.w : da.z)
                                                : ((j0 & 1) ? da.y : da.x));
                float bias = rstd * (dh - mu * sumA[j0]) + constB[j0];
                sc[(qq * NH + j0) * SROW + k] += bias;
            }
        };
        float4 A0 = zb0[rb], A1 = zb0[rb + 16];
        float4 B0 = zb1[rb], B1 = zb1[rb + 16];
        for (int g = 0; g < 64; ++g) {
            int gn = (g + 1) & 63;
            float4 N0 = zb0[rb + gn * 128];
            float4 N1 = zb0[rb + gn * 128 + 16];
            float4 M0 = zb1[rb + gn * 128];
            float4 M1 = zb1[rb + gn * 128 + 16];
            process(0, g, A0, A1);
            process(1, g, B0, B1);
            A0 = N0; A1 = N1; B0 = M0; B1 = M1;
        }
    }
    __syncthreads();

    // ---- phase C: softmax, 16 lanes per (q,head) row ----
    {
        int r = tid >> 4, j = tid & 15;
        float* srow = sc + r * SROW;
        float mx = -1e30f;
        #pragma unroll 4
        for (int i = 0; i < 64; ++i) mx = fmaxf(mx, srow[j + i * 16]);
        RED16MAX(mx);
        float sum = 0.f;
        #pragma unroll 4
        for (int i = 0; i < 64; ++i) {
            float e = __expf(srow[j + i * 16] - mx);
            srow[j + i * 16] = e;
            sum += e;
        }
        RED16(sum);
        if (j == 0) inv_lds[r] = 1.f / sum;
    }
    __syncthreads();

    // ---- phase D: o = P.V for both q rows (V tile read once) ----
    {
        const float4* V4 = (const float4*)VS;
        const int h = l >> 3;
        const float* p0 = sc + h * SROW;
        const float* p1 = sc + (NH + h) * SROW;
        float4 o0 = make_float4(0.f, 0.f, 0.f, 0.f);
        float4 o1 = make_float4(0.f, 0.f, 0.f, 0.f);
        for (int i = 0; i < 256; i += 4) {
            int k0 = (w << 8) + i;
            float4 v0 = V4[(size_t)(k0 + 0) * 64 + l];
            float4 v1 = V4[(size_t)(k0 + 1) * 64 + l];
            float4 v2 = V4[(size_t)(k0 + 2) * 64 + l];
            float4 v3 = V4[(size_t)(k0 + 3) * 64 + l];
            float4 pa = *(const float4*)(p0 + k0);
            float4 pb = *(const float4*)(p1 + k0);
            FMA4(o0, pa.x, v0); FMA4(o0, pa.y, v1); FMA4(o0, pa.z, v2); FMA4(o0, pa.w, v3);
            FMA4(o1, pb.x, v0); FMA4(o1, pb.y, v1); FMA4(o1, pb.z, v2); FMA4(o1, pb.w, v3);
        }
        ((float4*)aux)[w * 64 + l] = o0;
        ((float4*)aux)[256 + w * 64 + l] = o1;
    }
    __syncthreads();
    {
        #pragma unroll
        for (int qq = 0; qq < 2; ++qq) {
            int base = qq * 1024;
            float s = aux[base + tid] + aux[base + 256 + tid]
                    + aux[base + 512 + tid] + aux[base + 768 + tid];
            obr[qq][tid] = s * inv_lds[qq * 8 + (tid >> 5)]
                         * GS[(size_t)(q0 + qq) * CIN + tid];
        }
    }
    __syncthreads();

    // ---- phase E: fused out-projection: out[q] = obr[q] @ Wo + bo ----
    {
        float acc0 = bo[tid], acc1 = acc0;
        const float4* ob0 = (const float4*)obr[0];
        const float4* ob1 = (const float4*)obr[1];
        for (int c4 = 0; c4 < 64; ++c4) {
            float4 oa = ob0[c4];
            float4 obv = ob1[c4];
            float w0 = Wo[(c4 * 4 + 0) * 256 + tid];
            float w1 = Wo[(c4 * 4 + 1) * 256 + tid];
            float w2 = Wo[(c4 * 4 + 2) * 256 + tid];
            float w3 = Wo[(c4 * 4 + 3) * 256 + tid];
            acc0 += oa.x * w0 + oa.y * w1 + oa.z * w2 + oa.w * w3;
            acc1 += obv.x * w0 + obv.y * w1 + obv.z * w2 + obv.w * w3;
        }
        out[(size_t)q0 * CIN + tid] = acc0;
        out[(size_t)(q0 + 1) * CIN + tid] = acc1;
    }
}

extern "C" void kernel_launch(void* const* d_in, const int* in_sizes, int n_in,
                              void* d_out, int out_size, void* d_ws, size_t ws_size,
                              hipStream_t stream) {
    (void)in_sizes; (void)n_in; (void)out_size; (void)ws_size;
    const float* m   = (const float*)d_in[0];
    const float* z   = (const float*)d_in[1];
    const float* lmw = (const float*)d_in[2];
    const float* lmb = (const float*)d_in[3];
    const float* lzw = (const float*)d_in[4];
    const float* lzb = (const float*)d_in[5];
    const float* Wz  = (const float*)d_in[6];
    const float* Wq  = (const float*)d_in[7];
    const float* Wk  = (const float*)d_in[8];
    const float* Wv  = (const float*)d_in[9];
    const float* Wg  = (const float*)d_in[10];
    const float* Wo  = (const float*)d_in[12];
    const float* bo  = (const float*)d_in[13];
    float* ws = (float*)d_ws;
    float* QS = ws;
    float* KS = ws + 262144;
    float* VS = ws + 524288;
    float* GS = ws + 786432;
    float* out = (float*)d_out;

    static int attr_done = 0;
    const int dyn_bytes = 2 * NH * SROW * 4;   // 65792 B
    if (!attr_done) {
        hipFuncSetAttribute((const void*)k_attn,
                            hipFuncAttributeMaxDynamicSharedMemorySize, dyn_bytes);
        attr_done = 1;
    }

    hipLaunchKernelGGL(k_qkvg, dim3(512), dim3(256), 0, stream,
                       m, lmw, lmb, Wq, Wk, Wv, Wg, QS, KS, VS, GS);
    hipLaunchKernelGGL(k_attn, dim3(R / 2), dim3(256), dyn_bytes, stream,
                       z, lzw, lzb, Wz, QS, KS, VS, GS, Wo, bo, out);
}

// Round 4
// 776.147 us; speedup vs baseline: 1.0790x; 1.0314x over previous
//
#include <hip/hip_runtime.h>
#include <math.h>

#define R 1024
#define CIN 256
#define NH 8
#define CZ 128
#define EPS 1e-5f
#define SROW 1028  // score row stride: 16B-aligned, per-row bank offset 4

// ---- DPP cross-lane reductions (VALU pipe, no DS traffic) ----
#define DPPADD(v, ctrl) \
    v += __int_as_float(__builtin_amdgcn_update_dpp(0, __float_as_int(v), ctrl, 0xf, 0xf, true))
#define RED16(v)    { DPPADD(v, 0xB1); DPPADD(v, 0x4E); DPPADD(v, 0x141); DPPADD(v, 0x140); }
#define RED8(v)     { DPPADD(v, 0xB1); DPPADD(v, 0x4E); DPPADD(v, 0x141); }

// ---------------- K1: fused LN(m) + one of {Q,K,V,G} per block, 8 q-rows ----------------
// 512 blocks = 4 mats x 128 row-groups. Halves W L2 traffic vs 4-row blocks.
__global__ __launch_bounds__(256) void k_qkvg(const float* __restrict__ m,
        const float* __restrict__ lmw, const float* __restrict__ lmb,
        const float* __restrict__ Wq, const float* __restrict__ Wk,
        const float* __restrict__ Wv, const float* __restrict__ Wg,
        float* __restrict__ QS, float* __restrict__ KS,
        float* __restrict__ VS, float* __restrict__ GS) {
    __shared__ __align__(16) float mnt[CIN * 8];   // mnt[c][r], r=0..7
    __shared__ float red[64];                      // [wave][{s1[8],s2[8]}]
    int tid = threadIdx.x;
    int mat = blockIdx.x >> 7;            // 0..3
    int qb = (blockIdx.x & 127) * 8;

    float w_ln = lmw[tid], b_ln = lmb[tid];
    float x[8];
    #pragma unroll
    for (int r = 0; r < 8; ++r) x[r] = m[(size_t)(qb + r) * CIN + tid];
    #pragma unroll
    for (int r = 0; r < 8; ++r) {
        float a = x[r], bq = x[r] * x[r];
        RED16(a); RED16(bq);
        a += __shfl_xor(a, 16); bq += __shfl_xor(bq, 16);
        a += __shfl_xor(a, 32); bq += __shfl_xor(bq, 32);
        if ((tid & 63) == 0) { red[(tid >> 6) * 16 + r] = a; red[(tid >> 6) * 16 + 8 + r] = bq; }
    }
    __syncthreads();
    #pragma unroll
    for (int r = 0; r < 8; ++r) {
        float t1 = red[r] + red[16 + r] + red[32 + r] + red[48 + r];
        float t2 = red[8 + r] + red[24 + r] + red[40 + r] + red[56 + r];
        float mu = t1 * (1.0f / CIN);
        float var = t2 * (1.0f / CIN) - mu * mu;
        float rstd = rsqrtf(var + EPS);
        mnt[tid * 8 + r] = (x[r] - mu) * rstd * w_ln + b_ln;
    }
    __syncthreads();

    const float* W = (mat == 0) ? Wq : (mat == 1) ? Wk : (mat == 2) ? Wv : Wg;
    const float4* mt4 = (const float4*)mnt;       // 2 float4 per c
    float acc[8] = {0.f, 0.f, 0.f, 0.f, 0.f, 0.f, 0.f, 0.f};
    #pragma unroll 2
    for (int g = 0; g < 32; ++g) {
        float wv[8];
        #pragma unroll
        for (int u = 0; u < 8; ++u) wv[u] = W[(g * 8 + u) * 256 + tid];
        #pragma unroll
        for (int u = 0; u < 8; ++u) {
            float4 m0 = mt4[(g * 8 + u) * 2];
            float4 m1 = mt4[(g * 8 + u) * 2 + 1];
            acc[0] += m0.x * wv[u]; acc[1] += m0.y * wv[u];
            acc[2] += m0.z * wv[u]; acc[3] += m0.w * wv[u];
            acc[4] += m1.x * wv[u]; acc[5] += m1.y * wv[u];
            acc[6] += m1.z * wv[u]; acc[7] += m1.w * wv[u];
        }
    }
    float* OUT = (mat == 0) ? QS : (mat == 1) ? KS : (mat == 2) ? VS : GS;
    #pragma unroll
    for (int r = 0; r < 8; ++r) {
        float v = acc[r];
        if (mat == 0) v *= 0.17677669529663687f;      // 1/sqrt(32)
        if (mat == 3) v = 1.f / (1.f + __expf(-v));   // sigmoid
        OUT[(qb + r) * 256 + tid] = v;
    }
}

#define FMA4(acc, s, c) { acc.x += (s)*(c).x; acc.y += (s)*(c).y; \
                          acc.z += (s)*(c).z; acc.w += (s)*(c).w; }

// ---------------- K2: fused pair-bias(z) + attention + gate + out-proj ----------------
// QK^T merged INTO the z-stream loop: K reads (L2) + score math hide under the
// HBM-bound z stream; per-wave k-ownership makes the A->B dependency wave-local.
__global__ __launch_bounds__(256, 2) void k_attn(
        const float* __restrict__ z, const float* __restrict__ lzw,
        const float* __restrict__ lzb, const float* __restrict__ Wz,
        const float* __restrict__ QS, const float* __restrict__ KS,
        const float* __restrict__ VS, const float* __restrict__ GS,
        const float* __restrict__ Wo, const float* __restrict__ bo,
        float* __restrict__ out) {
    extern __shared__ __align__(16) float sc[];        // [2*NH][SROW] scores (65792 B)
    __shared__ __align__(16) float aux[2048];          // prep A (1024), then PV partials
    __shared__ __align__(16) float obr[2][CIN];        // gated attention output rows
    __shared__ float sumA[NH], constB[NH], inv_lds[16], wmax[64];  // wmax[qq*32+w*8+h]
    const int tid = threadIdx.x;
    const int q0 = blockIdx.x * 2;
    const int w = tid >> 6;     // wave 0..3, owns k in [w*256, w*256+256)
    const int l = tid & 63;
    const int j0 = l & 15;
    const int row = l >> 4;

    // ---- prep: A[c][h] = lzw[c] * Wz[c][h] ----
    if (tid < CZ) {
        float lw = lzw[tid];
        #pragma unroll
        for (int h = 0; h < NH; ++h) aux[tid * NH + h] = lw * Wz[tid * NH + h];
    }
    __syncthreads();
    if (tid < NH) {
        float sa = 0.f, cb = 0.f;
        for (int c = 0; c < CZ; ++c) {
            sa += aux[c * NH + tid];
            cb += lzb[c] * Wz[c * NH + tid];
        }
        sumA[tid] = sa; constB[tid] = cb;
    }
    float4 al[2][4][2];
    #pragma unroll
    for (int u = 0; u < 2; ++u)
        #pragma unroll
        for (int e = 0; e < 4; ++e) {
            int c = j0 * 4 + u * 64 + e;
            al[u][e][0] = *(const float4*)(aux + c * NH);
            al[u][e][1] = *(const float4*)(aux + c * NH + 4);
        }
    __syncthreads();   // aux fully consumed into registers

    // ---- merged phase A+B: scores = q.k + bias(z), single HBM-bound loop ----
    float mx0 = -1e30f, mx1 = -1e30f;   // per-lane running max of final scores
    {
        const float4 qa = ((const float4*)(QS + (size_t)q0 * CIN))[l];
        const float4 qb = ((const float4*)(QS + (size_t)(q0 + 1) * CIN))[l];
        const float4* K4 = (const float4*)KS;
        const int h = l >> 3;
        float* sd0 = sc + h * SROW;
        float* sd1 = sc + (NH + h) * SROW;
        const float4* zb0 = (const float4*)(z + ((size_t)q0 * R + (size_t)(w << 8)) * CZ);
        const float4* zb1 = zb0 + (size_t)R * CZ / 4;
        const int rb = row * 32 + j0;

        auto process = [&](int qq, int g, const float4 v0, const float4 v1) {
            int k = (w << 8) + (g << 2) + row;
            float s1 = v0.x + v0.y + v0.z + v0.w + v1.x + v1.y + v1.z + v1.w;
            float s2 = v0.x*v0.x + v0.y*v0.y + v0.z*v0.z + v0.w*v0.w
                     + v1.x*v1.x + v1.y*v1.y + v1.z*v1.z + v1.w*v1.w;
            float4 da = make_float4(0.f, 0.f, 0.f, 0.f);
            float4 db = make_float4(0.f, 0.f, 0.f, 0.f);
            FMA4(da, v0.x, al[0][0][0]); FMA4(db, v0.x, al[0][0][1]);
            FMA4(da, v0.y, al[0][1][0]); FMA4(db, v0.y, al[0][1][1]);
            FMA4(da, v0.z, al[0][2][0]); FMA4(db, v0.z, al[0][2][1]);
            FMA4(da, v0.w, al[0][3][0]); FMA4(db, v0.w, al[0][3][1]);
            FMA4(da, v1.x, al[1][0][0]); FMA4(db, v1.x, al[1][0][1]);
            FMA4(da, v1.y, al[1][1][0]); FMA4(db, v1.y, al[1][1][1]);
            FMA4(da, v1.z, al[1][2][0]); FMA4(db, v1.z, al[1][2][1]);
            FMA4(da, v1.w, al[1][3][0]); FMA4(db, v1.w, al[1][3][1]);
            RED16(s1);   RED16(s2);
            RED16(da.x); RED16(da.y); RED16(da.z); RED16(da.w);
            RED16(db.x); RED16(db.y); RED16(db.z); RED16(db.w);
            float mu = s1 * (1.0f / CZ);
            float var = s2 * (1.0f / CZ) - mu * mu;
            float rstd = rsqrtf(var + EPS);
            if (j0 < 8) {
                float dh = (j0 & 4) ? ((j0 & 2) ? ((j0 & 1) ? db.w : db.z)
                                                : ((j0 & 1) ? db.y : db.x))
                                    : ((j0 & 2) ? ((j0 & 1) ? da.w : da.z)
                                                : ((j0 & 1) ? da.y : da.x));
                float bias = rstd * (dh - mu * sumA[j0]) + constB[j0];
                float* p = sc + (qq * NH + j0) * SROW + k;
                float tot = *p + bias;
                *p = tot;
                float& mx = qq ? mx1 : mx0;
                mx = fmaxf(mx, tot);
            }
        };

        // prologue: loads for g=0
        float4 kc0 = K4[(size_t)((w << 8) + 0) * 64 + l];
        float4 kc1 = K4[(size_t)((w << 8) + 1) * 64 + l];
        float4 kc2 = K4[(size_t)((w << 8) + 2) * 64 + l];
        float4 kc3 = K4[(size_t)((w << 8) + 3) * 64 + l];
        float4 A0 = zb0[rb], A1 = zb0[rb + 16];
        float4 B0 = zb1[rb], B1 = zb1[rb + 16];

        for (int g = 0; g < 64; ++g) {
            int gn = (g + 1) & 63;
            int kn = (w << 8) + gn * 4;
            float4 n0 = K4[(size_t)(kn + 0) * 64 + l];
            float4 n1 = K4[(size_t)(kn + 1) * 64 + l];
            float4 n2 = K4[(size_t)(kn + 2) * 64 + l];
            float4 n3 = K4[(size_t)(kn + 3) * 64 + l];
            float4 N0 = zb0[rb + gn * 128];
            float4 N1 = zb0[rb + gn * 128 + 16];
            float4 M0 = zb1[rb + gn * 128];
            float4 M1 = zb1[rb + gn * 128 + 16];

            // -- QK^T for k0..k0+3 (both q rows), RED8 over 8-lane head groups --
            int kk = (w << 8) + g * 4;
            float d0a = kc0.x*qa.x + kc0.y*qa.y + kc0.z*qa.z + kc0.w*qa.w;
            float d1a = kc1.x*qa.x + kc1.y*qa.y + kc1.z*qa.z + kc1.w*qa.w;
            float d2a = kc2.x*qa.x + kc2.y*qa.y + kc2.z*qa.z + kc2.w*qa.w;
            float d3a = kc3.x*qa.x + kc3.y*qa.y + kc3.z*qa.z + kc3.w*qa.w;
            float d0b = kc0.x*qb.x + kc0.y*qb.y + kc0.z*qb.z + kc0.w*qb.w;
            float d1b = kc1.x*qb.x + kc1.y*qb.y + kc1.z*qb.z + kc1.w*qb.w;
            float d2b = kc2.x*qb.x + kc2.y*qb.y + kc2.z*qb.z + kc2.w*qb.w;
            float d3b = kc3.x*qb.x + kc3.y*qb.y + kc3.z*qb.z + kc3.w*qb.w;
            RED8(d0a); RED8(d1a); RED8(d2a); RED8(d3a);
            RED8(d0b); RED8(d1b); RED8(d2b); RED8(d3b);
            if ((l & 7) == 0) {
                *(float4*)(sd0 + kk) = make_float4(d0a, d1a, d2a, d3a);
                *(float4*)(sd1 + kk) = make_float4(d0b, d1b, d2b, d3b);
            }
            // -- pair bias for the same 4 k rows (reads the scores just written) --
            process(0, g, A0, A1);
            process(1, g, B0, B1);

            kc0 = n0; kc1 = n1; kc2 = n2; kc3 = n3;
            A0 = N0; A1 = N1; B0 = M0; B1 = M1;
        }

        // wave-level max reduce across the 4 row-groups (lanes sharing j0)
        mx0 = fmaxf(mx0, __shfl_xor(mx0, 16));
        mx0 = fmaxf(mx0, __shfl_xor(mx0, 32));
        mx1 = fmaxf(mx1, __shfl_xor(mx1, 16));
        mx1 = fmaxf(mx1, __shfl_xor(mx1, 32));
        if (l < 8) { wmax[w * 8 + l] = mx0; wmax[32 + w * 8 + l] = mx1; }
    }
    __syncthreads();

    // ---- phase C: softmax, single pass (max already known), 16 lanes/row ----
    {
        int r = tid >> 4, j = tid & 15;   // r = qq*8 + h
        int qq = r >> 3, h = r & 7;
        float mx = fmaxf(fmaxf(wmax[qq * 32 + h],      wmax[qq * 32 + 8 + h]),
                         fmaxf(wmax[qq * 32 + 16 + h], wmax[qq * 32 + 24 + h]));
        float* srow = sc + r * SROW;
        float sum = 0.f;
        #pragma unroll 4
        for (int i = 0; i < 64; ++i) {
            float e = __expf(srow[j + i * 16] - mx);
            srow[j + i * 16] = e;
            sum += e;
        }
        RED16(sum);
        if (j == 0) inv_lds[r] = 1.f / sum;
    }
    __syncthreads();

    // ---- phase D: o = P.V for both q rows (V tile read once) ----
    {
        const float4* V4 = (const float4*)VS;
        const int h = l >> 3;
        const float* p0 = sc + h * SROW;
        const float* p1 = sc + (NH + h) * SROW;
        float4 o0 = make_float4(0.f, 0.f, 0.f, 0.f);
        float4 o1 = make_float4(0.f, 0.f, 0.f, 0.f);
        for (int i = 0; i < 256; i += 4) {
            int k0 = (w << 8) + i;
            float4 v0 = V4[(size_t)(k0 + 0) * 64 + l];
            float4 v1 = V4[(size_t)(k0 + 1) * 64 + l];
            float4 v2 = V4[(size_t)(k0 + 2) * 64 + l];
            float4 v3 = V4[(size_t)(k0 + 3) * 64 + l];
            float4 pa = *(const float4*)(p0 + k0);
            float4 pb = *(const float4*)(p1 + k0);
            FMA4(o0, pa.x, v0); FMA4(o0, pa.y, v1); FMA4(o0, pa.z, v2); FMA4(o0, pa.w, v3);
            FMA4(o1, pb.x, v0); FMA4(o1, pb.y, v1); FMA4(o1, pb.z, v2); FMA4(o1, pb.w, v3);
        }
        ((float4*)aux)[w * 64 + l] = o0;
        ((float4*)aux)[256 + w * 64 + l] = o1;
    }
    __syncthreads();
    {
        #pragma unroll
        for (int qq = 0; qq < 2; ++qq) {
            int base = qq * 1024;
            float s = aux[base + tid] + aux[base + 256 + tid]
                    + aux[base + 512 + tid] + aux[base + 768 + tid];
            obr[qq][tid] = s * inv_lds[qq * 8 + (tid >> 5)]
                         * GS[(size_t)(q0 + qq) * CIN + tid];
        }
    }
    __syncthreads();

    // ---- phase E: fused out-projection: out[q] = obr[q] @ Wo + bo ----
    {
        float acc0 = bo[tid], acc1 = acc0;
        const float4* ob0 = (const float4*)obr[0];
        const float4* ob1 = (const float4*)obr[1];
        for (int c4 = 0; c4 < 64; ++c4) {
            float4 oa = ob0[c4];
            float4 obv = ob1[c4];
            float w0 = Wo[(c4 * 4 + 0) * 256 + tid];
            float w1 = Wo[(c4 * 4 + 1) * 256 + tid];
            float w2 = Wo[(c4 * 4 + 2) * 256 + tid];
            float w3 = Wo[(c4 * 4 + 3) * 256 + tid];
            acc0 += oa.x * w0 + oa.y * w1 + oa.z * w2 + oa.w * w3;
            acc1 += obv.x * w0 + obv.y * w1 + obv.z * w2 + obv.w * w3;
        }
        out[(size_t)q0 * CIN + tid] = acc0;
        out[(size_t)(q0 + 1) * CIN + tid] = acc1;
    }
}

extern "C" void kernel_launch(void* const* d_in, const int* in_sizes, int n_in,
                              void* d_out, int out_size, void* d_ws, size_t ws_size,
                              hipStream_t stream) {
    (void)in_sizes; (void)n_in; (void)out_size; (void)ws_size;
    const float* m   = (const float*)d_in[0];
    const float* z   = (const float*)d_in[1];
    const float* lmw = (const float*)d_in[2];
    const float* lmb = (const float*)d_in[3];
    const float* lzw = (const float*)d_in[4];
    const float* lzb = (const float*)d_in[5];
    const float* Wz  = (const float*)d_in[6];
    const float* Wq  = (const float*)d_in[7];
    const float* Wk  = (const float*)d_in[8];
    const float* Wv  = (const float*)d_in[9];
    const float* Wg  = (const float*)d_in[10];
    const float* Wo  = (const float*)d_in[12];
    const float* bo  = (const float*)d_in[13];
    float* ws = (float*)d_ws;
    float* QS = ws;
    float* KS = ws + 262144;
    float* VS = ws + 524288;
    float* GS = ws + 786432;
    float* out = (float*)d_out;

    static int attr_done = 0;
    const int dyn_bytes = 2 * NH * SROW * 4;   // 65792 B
    if (!attr_done) {
        hipFuncSetAttribute((const void*)k_attn,
                            hipFuncAttributeMaxDynamicSharedMemorySize, dyn_bytes);
        attr_done = 1;
    }

    hipLaunchKernelGGL(k_qkvg, dim3(512), dim3(256), 0, stream,
                       m, lmw, lmb, Wq, Wk, Wv, Wg, QS, KS, VS, GS);
    hipLaunchKernelGGL(k_attn, dim3(R / 2), dim3(256), dyn_bytes, stream,
                       z, lzw, lzb, Wz, QS, KS, VS, GS, Wo, bo, out);
}